// Round 7
// baseline (191.809 us; speedup 1.0000x reference)
//
#include <hip/hip_runtime.h>

#define NB   4
#define SEQ  4096
#define EMB  1024
#define HS   64

typedef __attribute__((ext_vector_type(8))) short bf16x8;   // 8 bf16 = 4 VGPRs
typedef __attribute__((ext_vector_type(4))) float f32x4;    // MFMA C/D

__device__ inline unsigned short f2bf(float f) {  // fp32 -> bf16 RNE
  unsigned int u = __float_as_uint(f);
  u += 0x7fffu + ((u >> 16) & 1u);
  return (unsigned short)(u >> 16);
}
__device__ inline float bf2f(unsigned short h) {
  return __uint_as_float(((unsigned int)h) << 16);
}
// same for [row][32] tiles (4 chunks/row, swizzle over (row>>1)&3)
__device__ inline int swzi32(int row, int c) {
  return row * 32 + ((c ^ ((row >> 1) & 3)) << 3);
}
// [row][128] tiles (16 chunks/row, swizzle over row&7)
__device__ inline int swzi128(int row, int c) {
  return row * 128 + ((c ^ (row & 7)) << 3);
}
// Async global->LDS 16B. LDS dest wave-uniform; lane i lands at +16*i.
__device__ inline void gld16(const unsigned short* g, unsigned short* l) {
  __builtin_amdgcn_global_load_lds(
      (const __attribute__((address_space(1))) void*)g,
      (__attribute__((address_space(3))) void*)l, 16, 0, 0);
}

// ---------------------------------------------------------------------------
// W prep: split Wq*scale*log2e | Wk | Wv into bf16 hi/lo [192][1024].
// ---------------------------------------------------------------------------
__global__ __launch_bounds__(256) void wprep(
    const float* __restrict__ Wk, const float* __restrict__ Wq,
    const float* __restrict__ Wv,
    unsigned short* __restrict__ Wh, unsigned short* __restrict__ Wl) {
  int i = blockIdx.x * 256 + threadIdx.x;  // float4 id, 192*1024/4 = 49152
  int e = i >> 8, c = i & 255;
  float4 v;
  float sc = 1.0f;
  if (e < 64)       { v = ((const float4*)Wq)[e * 256 + c];
                      sc = 0.18033688011112042f; }  // (1/sqrt(64))*log2(e)
  else if (e < 128)   v = ((const float4*)Wk)[(e - 64) * 256 + c];
  else                v = ((const float4*)Wv)[(e - 128) * 256 + c];
  v.x *= sc; v.y *= sc; v.z *= sc; v.w *= sc;
  ushort4 hv, lv;
  hv.x = f2bf(v.x); lv.x = f2bf(v.x - bf2f(hv.x));
  hv.y = f2bf(v.y); lv.y = f2bf(v.y - bf2f(hv.y));
  hv.z = f2bf(v.z); lv.z = f2bf(v.z - bf2f(hv.z));
  hv.w = f2bf(v.w); lv.w = f2bf(v.w - bf2f(hv.w));
  *(ushort4*)&Wh[i * 4] = hv;
  *(ushort4*)&Wl[i * 4] = lv;
}

// ---------------------------------------------------------------------------
// Single-pass fused QKV GEMM (round-2 structure, best measured):
// counted-vmcnt pipeline; loop barrier = raw lgkmcnt(0)+s_barrier.
// ---------------------------------------------------------------------------
#define XhSp(p) ((unsigned short*)(SM + (p) * 2048))
#define XlSp(p) ((unsigned short*)(SM + 4096 + (p) * 2048))
#define WhSp(p) ((unsigned short*)(SM + 8192 + (p) * 12288))
#define WlSp(p) ((unsigned short*)(SM + 32768 + (p) * 12288))

__global__ __launch_bounds__(256) void qkv_x1(
    const float* __restrict__ x,
    const unsigned short* __restrict__ Wh, const unsigned short* __restrict__ Wl,
    unsigned short* __restrict__ qh, unsigned short* __restrict__ ql,
    unsigned short* __restrict__ kh, unsigned short* __restrict__ kl,
    unsigned short* __restrict__ vt) {
  __shared__ __align__(16) unsigned char SM[57344];

  const int t  = threadIdx.x;
  const int l  = t & 63;
  const int li = l & 15;
  const int g  = l >> 4;
  const int w  = t >> 6;         // 0..3
  const int m0 = blockIdx.x * 32;
  const int b  = m0 >> 12;
  const int n0 = m0 & 4095;

  const int xrow = t >> 3;
  const float* xp = x + (m0 + xrow) * EMB + (t & 7) * 4;
  const int xaddr = xrow * 32 + ((((t & 7) >> 1) ^ ((xrow >> 1) & 3)) << 3)
                    + (t & 1) * 4;

  const int wconst = (l >> 2) * EMB + (((l & 3) ^ ((l >> 3) & 3)) << 3);

  f32x4 acc[2][3];
#pragma unroll
  for (int i = 0; i < 2; ++i)
#pragma unroll
    for (int j = 0; j < 3; ++j) acc[i][j] = (f32x4){0.f, 0.f, 0.f, 0.f};

  const int rA0 = li, rA1 = 16 + li;
  const int rB0 = 48 * w + li, rB1 = rB0 + 16, rB2 = rB0 + 32;

  auto issueW = [&](int s, int p) {
    const int ko = s * 32;
#pragma unroll
    for (int i = 0; i < 3; ++i) {
      const int seg = 3 * w + i;
      gld16(Wh + 16 * seg * EMB + wconst + ko, WhSp(p) + seg * 512);
      gld16(Wl + 16 * seg * EMB + wconst + ko, WlSp(p) + seg * 512);
    }
  };
  auto writeX = [&](float4 v, int p) {
    unsigned short h0 = f2bf(v.x), h1 = f2bf(v.y), h2 = f2bf(v.z), h3 = f2bf(v.w);
    unsigned short e0 = f2bf(v.x - bf2f(h0)), e1 = f2bf(v.y - bf2f(h1));
    unsigned short e2 = f2bf(v.z - bf2f(h2)), e3 = f2bf(v.w - bf2f(h3));
    int2 hv, lv;
    hv.x = (int)((unsigned)h0 | ((unsigned)h1 << 16));
    hv.y = (int)((unsigned)h2 | ((unsigned)h3 << 16));
    lv.x = (int)((unsigned)e0 | ((unsigned)e1 << 16));
    lv.y = (int)((unsigned)e2 | ((unsigned)e3 << 16));
    *(int2*)&XhSp(p)[xaddr] = hv;
    *(int2*)&XlSp(p)[xaddr] = lv;
  };

  float4 px = *(const float4*)xp;     // stage 0
  issueW(0, 0);
  writeX(px, 0);
  px = *(const float4*)(xp + 32);     // stage 1
  __syncthreads();                    // full drain ONCE: W(0)+x(0) landed

  for (int s = 0; s < 32; ++s) {
    const int p = s & 1;
    if (s < 31) {
      issueW(s + 1, p ^ 1);           // 6 gld16 -- fly across the barrier
      writeX(px, p ^ 1);              // px-use auto-waits vmcnt(6): W(s) landed
      if (s < 30) px = *(const float4*)(xp + (s + 2) * 32);
    } else {
      asm volatile("s_waitcnt vmcnt(0)" ::: "memory");  // tail: W(31) landed
    }
    __builtin_amdgcn_sched_barrier(0);  // ds_reads must stay below the waits

    bf16x8 ah0 = *(const bf16x8*)&XhSp(p)[swzi32(rA0, g)];
    bf16x8 ah1 = *(const bf16x8*)&XhSp(p)[swzi32(rA1, g)];
    bf16x8 al0 = *(const bf16x8*)&XlSp(p)[swzi32(rA0, g)];
    bf16x8 al1 = *(const bf16x8*)&XlSp(p)[swzi32(rA1, g)];
    bf16x8 bh0 = *(const bf16x8*)&WhSp(p)[swzi32(rB0, g)];
    bf16x8 bh1 = *(const bf16x8*)&WhSp(p)[swzi32(rB1, g)];
    bf16x8 bh2 = *(const bf16x8*)&WhSp(p)[swzi32(rB2, g)];
    bf16x8 bl0 = *(const bf16x8*)&WlSp(p)[swzi32(rB0, g)];
    bf16x8 bl1 = *(const bf16x8*)&WlSp(p)[swzi32(rB1, g)];
    bf16x8 bl2 = *(const bf16x8*)&WlSp(p)[swzi32(rB2, g)];

    __builtin_amdgcn_s_setprio(1);
    acc[0][0] = __builtin_amdgcn_mfma_f32_16x16x32_bf16(ah0, bh0, acc[0][0], 0,0,0);
    acc[0][0] = __builtin_amdgcn_mfma_f32_16x16x32_bf16(ah0, bl0, acc[0][0], 0,0,0);
    acc[0][0] = __builtin_amdgcn_mfma_f32_16x16x32_bf16(al0, bh0, acc[0][0], 0,0,0);
    acc[0][1] = __builtin_amdgcn_mfma_f32_16x16x32_bf16(ah0, bh1, acc[0][1], 0,0,0);
    acc[0][1] = __builtin_amdgcn_mfma_f32_16x16x32_bf16(ah0, bl1, acc[0][1], 0,0,0);
    acc[0][1] = __builtin_amdgcn_mfma_f32_16x16x32_bf16(al0, bh1, acc[0][1], 0,0,0);
    acc[0][2] = __builtin_amdgcn_mfma_f32_16x16x32_bf16(ah0, bh2, acc[0][2], 0,0,0);
    acc[0][2] = __builtin_amdgcn_mfma_f32_16x16x32_bf16(ah0, bl2, acc[0][2], 0,0,0);
    acc[0][2] = __builtin_amdgcn_mfma_f32_16x16x32_bf16(al0, bh2, acc[0][2], 0,0,0);
    acc[1][0] = __builtin_amdgcn_mfma_f32_16x16x32_bf16(ah1, bh0, acc[1][0], 0,0,0);
    acc[1][0] = __builtin_amdgcn_mfma_f32_16x16x32_bf16(ah1, bl0, acc[1][0], 0,0,0);
    acc[1][0] = __builtin_amdgcn_mfma_f32_16x16x32_bf16(al1, bh0, acc[1][0], 0,0,0);
    acc[1][1] = __builtin_amdgcn_mfma_f32_16x16x32_bf16(ah1, bh1, acc[1][1], 0,0,0);
    acc[1][1] = __builtin_amdgcn_mfma_f32_16x16x32_bf16(ah1, bl1, acc[1][1], 0,0,0);
    acc[1][1] = __builtin_amdgcn_mfma_f32_16x16x32_bf16(al1, bh1, acc[1][1], 0,0,0);
    acc[1][2] = __builtin_amdgcn_mfma_f32_16x16x32_bf16(ah1, bh2, acc[1][2], 0,0,0);
    acc[1][2] = __builtin_amdgcn_mfma_f32_16x16x32_bf16(ah1, bl2, acc[1][2], 0,0,0);
    acc[1][2] = __builtin_amdgcn_mfma_f32_16x16x32_bf16(al1, bh2, acc[1][2], 0,0,0);
    __builtin_amdgcn_s_setprio(0);

    asm volatile("s_waitcnt lgkmcnt(0)" ::: "memory");
    __builtin_amdgcn_s_barrier();
    __builtin_amdgcn_sched_barrier(0);
  }

  // Epilogue: D[m=16i+4g+r][n=48w+16j+li]
#pragma unroll
  for (int i = 0; i < 2; ++i)
#pragma unroll
    for (int j = 0; j < 3; ++j) {
      const int H3 = 48 * w + 16 * j + li;
#pragma unroll
      for (int r = 0; r < 4; ++r) {
        const int mrow = 16 * i + 4 * g + r;
        const float vv = acc[i][j][r];
        if (H3 < 64) {
          const unsigned short hb = f2bf(vv);
          const int off = (b * SEQ + n0 + mrow) * HS + H3;
          qh[off] = hb; ql[off] = f2bf(vv - bf2f(hb));
        } else if (H3 < 128) {
          const unsigned short hb = f2bf(vv);
          const int off = (b * SEQ + n0 + mrow) * HS + (H3 - 64);
          kh[off] = hb; kl[off] = f2bf(vv - bf2f(hb));
        } else {
          vt[(b * HS + (H3 - 128)) * SEQ + n0 + mrow] = f2bf(vv);
        }
      }
    }
}

// ---------------------------------------------------------------------------
// Flash attention, round 7: K NEVER TOUCHES LDS.
// QK^T remap: wave w owns keys [16w,16w+16) x ALL 64 q (Q lives in regs, so
// zero redundancy). A-frag = contiguous ushort8 of kh/kl -> global->reg,
// double-buffered. Deletes 32KB/iter K staging + 64 ds_read_b128/iter (the
// LDS unit was ~63% busy: 112 reads x 12cy + 984 conflict cy + writes).
// Pt is now CROSS-wave (writer (w,qs) -> slab (qs>>1)+2(w>>1)); legal since
// deferred-PV(t-1) reads the OTHER time-parity slab, ordered by the per-iter
// barrier. V stays LDS (3-buf, gld16); PV & merge unchanged.
// LDS 88KB; VGPR ~170 (Q 4 q-sets + K dbuf), still 2 waves/SIMD.
// ---------------------------------------------------------------------------
__global__ __launch_bounds__(512) void attn_mfma(
    const unsigned short* __restrict__ qh, const unsigned short* __restrict__ ql,
    const unsigned short* __restrict__ kh, const unsigned short* __restrict__ kl,
    const unsigned short* __restrict__ vt, float* __restrict__ out) {
  __shared__ __align__(16) unsigned char SM[90112];
  // layout: Vt[v] @ v*16384 (3x16KB) [0..48K)
  //         Pt @ 49152: 8 slabIdx x 2 time-slabs x 1280 ush = 40KB
  unsigned short* const PtS = (unsigned short*)(SM + 49152);

  const int t  = threadIdx.x;
  const int l  = t & 63;
  const int li = l & 15;
  const int g  = l >> 4;
  const int w  = t >> 6;        // 0..7
  const int b  = blockIdx.y;
  const int q0 = blockIdx.x << 6;

  // Persistent Q fragments, 4 q-sets (B[k=h][n=q], n=li) -- full 64 q.
  bf16x8 qfh[4][2], qfl[4][2];
#pragma unroll
  for (int qs = 0; qs < 4; ++qs) {
    const unsigned short* qrh = qh + (b * SEQ + q0 + 16 * qs + li) * HS;
    const unsigned short* qrl = ql + (b * SEQ + q0 + 16 * qs + li) * HS;
    qfh[qs][0] = *(const bf16x8*)&qrh[8 * g];
    qfh[qs][1] = *(const bf16x8*)&qrh[32 + 8 * g];
    qfl[qs][0] = *(const bf16x8*)&qrl[8 * g];
    qfl[qs][1] = *(const bf16x8*)&qrl[32 + 8 * g];
  }

  // K direct-to-reg row base: this wave's 16 keys, this lane's 16B slice.
  const unsigned short* const khR = kh + (b * SEQ + 16 * w + li) * HS + 8 * g;
  const unsigned short* const klR = kl + (b * SEQ + 16 * w + li) * HS + 8 * g;

  // V gld16 lane constants (segs: 4 h-rows x 128 keys = 1KB, parity perm).
  const int rowl = l >> 4, slot = l & 15;
  const int vcE = rowl * SEQ + ((slot ^ rowl) << 3);
  const int vcO = rowl * SEQ + ((slot ^ (4 + rowl)) << 3);
  const unsigned short* vtB = vt + b * HS * SEQ;
  const int sA = 2 * w, sB = 2 * w + 1;   // this wave's 2 V segs

  f32x4 O[4][2];
#pragma unroll
  for (int ht = 0; ht < 4; ++ht) {
    O[ht][0] = (f32x4){0.f, 0.f, 0.f, 0.f};
    O[ht][1] = (f32x4){0.f, 0.f, 0.f, 0.f};
  }
  float lp[4] = {0.f, 0.f, 0.f, 0.f};

  // Pt write constants (cross-wave): slabIdx low bit = qs>>1, high = w>>1.
  const int slabBase = (w & ~1);          // 2*(w>>1)
  const int cW = 2 * (w & 1) + (g >> 1);  // chunk within 32-key slab
  const int subW = (g & 1) << 2;          // int2 offset within chunk

  auto stageV = [&](int it, int vb) {
    const int kt0 = it << 7;
    unsigned short* const VtP = (unsigned short*)(SM + vb * 16384);
    gld16(vtB + 4 * sA * SEQ + kt0 + vcE, VtP + sA * 512);
    gld16(vtB + 4 * sB * SEQ + kt0 + vcO, VtP + sB * 512);
  };
  auto loadK = [&](int it, bf16x8 (&K)[4]) {
    const int off = (it << 7) * HS;       // tile base in ushorts
    K[0] = *(const bf16x8*)&khR[off];        // kh, h 0..31 slice
    K[1] = *(const bf16x8*)&khR[off + 32];   // kh, h 32..63 slice
    K[2] = *(const bf16x8*)&klR[off];        // kl, h 0..31
    K[3] = *(const bf16x8*)&klR[off + 32];   // kl, h 32..63
  };
  // PV of a prior tile: this wave = (qg=w&1, ks=w>>1), 32 keys x 32 q x 64 h.
  auto PV = [&](int slab, int vb) {
    const int ks = w >> 1;
    unsigned short* const PtP = PtS + w * 2560 + slab * 1280;
    unsigned short* const VtP = (unsigned short*)(SM + vb * 16384);
    bf16x8 pb0 = *(const bf16x8*)&PtP[li * 40 + ((g ^ (li & 3)) << 3)];
    const int r1 = 16 + li;
    bf16x8 pb1 = *(const bf16x8*)&PtP[r1 * 40 + ((g ^ (r1 & 3)) << 3)];
    __builtin_amdgcn_s_setprio(1);
#pragma unroll
    for (int ht = 0; ht < 4; ++ht) {
      const int vrow = 16 * ht + li;
      bf16x8 va = *(const bf16x8*)&VtP[swzi128(vrow, 4 * ks + g)];
      O[ht][0] = __builtin_amdgcn_mfma_f32_16x16x32_bf16(va, pb0, O[ht][0], 0,0,0);
      O[ht][1] = __builtin_amdgcn_mfma_f32_16x16x32_bf16(va, pb1, O[ht][1], 0,0,0);
    }
    __builtin_amdgcn_s_setprio(0);
  };

  bf16x8 Ka[4], Kb[4];
  loadK(0, Ka);
  stageV(0, 0);
  __syncthreads();            // V(0) in LDS; K(0) ordered by reg use-dep

  int vbn = 1;                // (it+1)%3
  int vbp = 2;                // (it-1)%3 (unused at it=0)

  auto iter = [&](int it, int p, bf16x8 (&Kc)[4], bf16x8 (&Kn)[4]) {
    if (it < 31) {
      loadK(it + 1, Kn);                 // global->reg, flies over the body
      stageV(it + 1, vbn);               // gld16, flies over the body
    }

    // QK^T(it): S[qs] = K(16 keys) . Q(16 q), keys = 16w + 4g + r.
    f32x4 S[4];
#pragma unroll
    for (int qs = 0; qs < 4; ++qs)
      S[qs] = (f32x4){-32.f, -32.f, -32.f, -32.f};
    __builtin_amdgcn_s_setprio(1);
#pragma unroll
    for (int khf = 0; khf < 2; ++khf) {
#pragma unroll
      for (int qs = 0; qs < 4; ++qs) {
        S[qs] = __builtin_amdgcn_mfma_f32_16x16x32_bf16(Kc[khf],     qfh[qs][khf], S[qs], 0,0,0);
        S[qs] = __builtin_amdgcn_mfma_f32_16x16x32_bf16(Kc[khf],     qfl[qs][khf], S[qs], 0,0,0);
        S[qs] = __builtin_amdgcn_mfma_f32_16x16x32_bf16(Kc[2 + khf], qfh[qs][khf], S[qs], 0,0,0);
      }
    }
    __builtin_amdgcn_s_setprio(0);

    // PV of PREVIOUS tile (reads other-parity Pt slab + V[vbp]); overlaps
    // the exp chain below (independent of S).
    if (it > 0) PV(p ^ 1, vbp);

    // exp2, truncate to bf16, write Pt (cross-wave slabs), accumulate l.
#pragma unroll
    for (int qs = 0; qs < 4; ++qs) {
      unsigned pu[4];
      float ls = 0.f;
#pragma unroll
      for (int r = 0; r < 4; ++r) {
        const float pe = exp2f(S[qs][r]);
        pu[r] = __float_as_uint(pe);
        ls += __uint_as_float(pu[r] & 0xffff0000u);
      }
      lp[qs] += ls;
      const unsigned p01 = __builtin_amdgcn_perm(pu[1], pu[0], 0x07060302u);
      const unsigned p23 = __builtin_amdgcn_perm(pu[3], pu[2], 0x07060302u);
      const int slabIdx = slabBase + (qs >> 1);
      const int qrow2 = 16 * (qs & 1) + li;
      const int addr = qrow2 * 40 + (((cW ^ (qrow2 & 3))) << 3) + subW;
      int2 pv; pv.x = (int)p01; pv.y = (int)p23;
      *(int2*)&PtS[slabIdx * 2560 + p * 1280 + addr] = pv;
    }

    // ONE barrier/iter: drains K(it+1) reg loads + V(it+1) gld16 (both had
    // the whole body in flight) and orders Pt/V buffer reuse.
    __syncthreads();

    vbn = (vbn == 2) ? 0 : vbn + 1;
    vbp = (vbp == 2) ? 0 : vbp + 1;
  };

  for (int t2 = 0; t2 < 16; ++t2) {
    iter(2 * t2,     0, Ka, Kb);
    iter(2 * t2 + 1, 1, Kb, Ka);
  }

  // Drain: PV of tile 31 (Pt time-slab 31&1=1, V[31%3=1]).
  PV(1, 1);
  __syncthreads();   // PV(31) reads done before merge overwrites V/Pt space

  // reduce l over g (this wave's 16 keys are spread over g-quads)
#pragma unroll
  for (int qs = 0; qs < 4; ++qs) {
    lp[qs] += __shfl_xor(lp[qs], 16);
    lp[qs] += __shfl_xor(lp[qs], 32);
  }

  float* const OTm = (float*)SM;               // [8 pv-waves][32 q][64 h] 64KB
  float* const Lm  = (float*)(SM + 65536);     // [8 qk-waves][64 q] 2KB
#pragma unroll
  for (int ht = 0; ht < 4; ++ht)
#pragma unroll
    for (int qs = 0; qs < 2; ++qs) {
      float4 o4;
      o4.x = O[ht][qs][0]; o4.y = O[ht][qs][1];
      o4.z = O[ht][qs][2]; o4.w = O[ht][qs][3];
      *(float4*)&OTm[w * 2048 + (16 * qs + li) * 64 + 16 * ht + 4 * g] = o4;
    }
  if (g == 0) {
#pragma unroll
    for (int qs = 0; qs < 4; ++qs) Lm[w * 64 + 16 * qs + li] = lp[qs];
  }
  __syncthreads();

  // final: thread t -> q = t>>3 (64), h8 = (t&7)*8.
  {
    const int q = t >> 3, h8 = (t & 7) << 3;
    const int qq = q & 31, qgf = q >> 5;
    float lF = 0.f;
#pragma unroll
    for (int ww = 0; ww < 8; ++ww) lF += Lm[ww * 64 + q];
    float4 a = {0.f, 0.f, 0.f, 0.f}, c4 = {0.f, 0.f, 0.f, 0.f};
#pragma unroll
    for (int k2 = 0; k2 < 4; ++k2) {
      const int ww = qgf + 2 * k2;      // PV wave with qg=qgf, ks=k2
      const float* Ob = OTm + ww * 2048 + qq * 64 + h8;
      float4 u = *(const float4*)Ob;
      float4 v = *(const float4*)(Ob + 4);
      a.x += u.x; a.y += u.y; a.z += u.z; a.w += u.w;
      c4.x += v.x; c4.y += v.y; c4.z += v.z; c4.w += v.w;
    }
    const float inv = 1.f / lF;
    a.x *= inv; a.y *= inv; a.z *= inv; a.w *= inv;
    c4.x *= inv; c4.y *= inv; c4.z *= inv; c4.w *= inv;
    float* op = out + (b * SEQ + q0 + q) * HS + h8;
    *(float4*)op = a;
    *(float4*)(op + 4) = c4;
  }
}

// ---------------------------------------------------------------------------
extern "C" void kernel_launch(void* const* d_in, const int* in_sizes, int n_in,
                              void* d_out, int out_size, void* d_ws,
                              size_t ws_size, hipStream_t stream) {
  const float* x  = (const float*)d_in[0];
  const float* Wk = (const float*)d_in[1];
  const float* Wq = (const float*)d_in[2];
  const float* Wv = (const float*)d_in[3];
  float* out = (float*)d_out;

  unsigned short* us = (unsigned short*)d_ws;
  unsigned short* qh = us + 0 * (1 << 20);   // [B][N][H] bf16 hi
  unsigned short* ql = us + 1 * (1 << 20);   // [B][N][H] bf16 lo
  unsigned short* kh = us + 2 * (1 << 20);
  unsigned short* kl = us + 3 * (1 << 20);
  unsigned short* vt = us + 4 * (1 << 20);   // [B][H][N] bf16
  unsigned short* Wh = us + 5 * (1 << 20);   // [192][1024] bf16 hi
  unsigned short* Wl = Wh + 192 * 1024;      // [192][1024] bf16 lo

  wprep<<<192, 256, 0, stream>>>(Wk, Wq, Wv, Wh, Wl);
  qkv_x1<<<512, 256, 0, stream>>>(x, Wh, Wl, qh, ql, kh, kl, vt);
  attn_mfma<<<dim3(64, NB), 512, 0, stream>>>(qh, ql, kh, kl, vt, out);
}

// Round 8
// 177.578 us; speedup vs baseline: 1.0801x; 1.0801x over previous
//
#include <hip/hip_runtime.h>

#define NB   4
#define SEQ  4096
#define EMB  1024
#define HS   64

typedef __attribute__((ext_vector_type(8))) short bf16x8;   // 8 bf16 = 4 VGPRs
typedef __attribute__((ext_vector_type(4))) float f32x4;    // MFMA C/D

__device__ inline unsigned short f2bf(float f) {  // fp32 -> bf16 RNE
  unsigned int u = __float_as_uint(f);
  u += 0x7fffu + ((u >> 16) & 1u);
  return (unsigned short)(u >> 16);
}
__device__ inline float bf2f(unsigned short h) {
  return __uint_as_float(((unsigned int)h) << 16);
}
// 16B-chunk index in a [row][64] bf16 LDS tile, XOR-swizzled over row&7.
__device__ inline int swzi64(int row, int c) {
  return row * 64 + ((c ^ (row & 7)) << 3);
}
// same for [row][32] tiles (4 chunks/row, swizzle over (row>>1)&3)
__device__ inline int swzi32(int row, int c) {
  return row * 32 + ((c ^ ((row >> 1) & 3)) << 3);
}
// [row][128] tiles (16 chunks/row, swizzle over row&7)
__device__ inline int swzi128(int row, int c) {
  return row * 128 + ((c ^ (row & 7)) << 3);
}
// Async global->LDS 16B. LDS dest wave-uniform; lane i lands at +16*i.
__device__ inline void gld16(const unsigned short* g, unsigned short* l) {
  __builtin_amdgcn_global_load_lds(
      (const __attribute__((address_space(1))) void*)g,
      (__attribute__((address_space(3))) void*)l, 16, 0, 0);
}

// ---------------------------------------------------------------------------
// W prep: split Wq*scale*log2e | Wk | Wv into bf16 hi/lo [192][1024].
// ---------------------------------------------------------------------------
__global__ __launch_bounds__(256) void wprep(
    const float* __restrict__ Wk, const float* __restrict__ Wq,
    const float* __restrict__ Wv,
    unsigned short* __restrict__ Wh, unsigned short* __restrict__ Wl) {
  int i = blockIdx.x * 256 + threadIdx.x;  // float4 id, 192*1024/4 = 49152
  int e = i >> 8, c = i & 255;
  float4 v;
  float sc = 1.0f;
  if (e < 64)       { v = ((const float4*)Wq)[e * 256 + c];
                      sc = 0.18033688011112042f; }  // (1/sqrt(64))*log2(e)
  else if (e < 128)   v = ((const float4*)Wk)[(e - 64) * 256 + c];
  else                v = ((const float4*)Wv)[(e - 128) * 256 + c];
  v.x *= sc; v.y *= sc; v.z *= sc; v.w *= sc;
  ushort4 hv, lv;
  hv.x = f2bf(v.x); lv.x = f2bf(v.x - bf2f(hv.x));
  hv.y = f2bf(v.y); lv.y = f2bf(v.y - bf2f(hv.y));
  hv.z = f2bf(v.z); lv.z = f2bf(v.z - bf2f(hv.z));
  hv.w = f2bf(v.w); lv.w = f2bf(v.w - bf2f(hv.w));
  *(ushort4*)&Wh[i * 4] = hv;
  *(ushort4*)&Wl[i * 4] = lv;
}

// ---------------------------------------------------------------------------
// Single-pass fused QKV GEMM (round-2 structure, best measured):
// counted-vmcnt pipeline; loop barrier = raw lgkmcnt(0)+s_barrier.
// ---------------------------------------------------------------------------
#define XhSp(p) ((unsigned short*)(SM + (p) * 2048))
#define XlSp(p) ((unsigned short*)(SM + 4096 + (p) * 2048))
#define WhSp(p) ((unsigned short*)(SM + 8192 + (p) * 12288))
#define WlSp(p) ((unsigned short*)(SM + 32768 + (p) * 12288))

__global__ __launch_bounds__(256) void qkv_x1(
    const float* __restrict__ x,
    const unsigned short* __restrict__ Wh, const unsigned short* __restrict__ Wl,
    unsigned short* __restrict__ qh, unsigned short* __restrict__ ql,
    unsigned short* __restrict__ kh, unsigned short* __restrict__ kl,
    unsigned short* __restrict__ vt) {
  __shared__ __align__(16) unsigned char SM[57344];

  const int t  = threadIdx.x;
  const int l  = t & 63;
  const int li = l & 15;
  const int g  = l >> 4;
  const int w  = t >> 6;         // 0..3
  const int m0 = blockIdx.x * 32;
  const int b  = m0 >> 12;
  const int n0 = m0 & 4095;

  const int xrow = t >> 3;
  const float* xp = x + (m0 + xrow) * EMB + (t & 7) * 4;
  const int xaddr = xrow * 32 + ((((t & 7) >> 1) ^ ((xrow >> 1) & 3)) << 3)
                    + (t & 1) * 4;

  const int wconst = (l >> 2) * EMB + (((l & 3) ^ ((l >> 3) & 3)) << 3);

  f32x4 acc[2][3];
#pragma unroll
  for (int i = 0; i < 2; ++i)
#pragma unroll
    for (int j = 0; j < 3; ++j) acc[i][j] = (f32x4){0.f, 0.f, 0.f, 0.f};

  const int rA0 = li, rA1 = 16 + li;
  const int rB0 = 48 * w + li, rB1 = rB0 + 16, rB2 = rB0 + 32;

  auto issueW = [&](int s, int p) {
    const int ko = s * 32;
#pragma unroll
    for (int i = 0; i < 3; ++i) {
      const int seg = 3 * w + i;
      gld16(Wh + 16 * seg * EMB + wconst + ko, WhSp(p) + seg * 512);
      gld16(Wl + 16 * seg * EMB + wconst + ko, WlSp(p) + seg * 512);
    }
  };
  auto writeX = [&](float4 v, int p) {
    unsigned short h0 = f2bf(v.x), h1 = f2bf(v.y), h2 = f2bf(v.z), h3 = f2bf(v.w);
    unsigned short e0 = f2bf(v.x - bf2f(h0)), e1 = f2bf(v.y - bf2f(h1));
    unsigned short e2 = f2bf(v.z - bf2f(h2)), e3 = f2bf(v.w - bf2f(h3));
    int2 hv, lv;
    hv.x = (int)((unsigned)h0 | ((unsigned)h1 << 16));
    hv.y = (int)((unsigned)h2 | ((unsigned)h3 << 16));
    lv.x = (int)((unsigned)e0 | ((unsigned)e1 << 16));
    lv.y = (int)((unsigned)e2 | ((unsigned)e3 << 16));
    *(int2*)&XhSp(p)[xaddr] = hv;
    *(int2*)&XlSp(p)[xaddr] = lv;
  };

  float4 px = *(const float4*)xp;     // stage 0
  issueW(0, 0);
  writeX(px, 0);
  px = *(const float4*)(xp + 32);     // stage 1
  __syncthreads();                    // full drain ONCE: W(0)+x(0) landed

  for (int s = 0; s < 32; ++s) {
    const int p = s & 1;
    if (s < 31) {
      issueW(s + 1, p ^ 1);           // 6 gld16 -- fly across the barrier
      writeX(px, p ^ 1);              // px-use auto-waits vmcnt(6): W(s) landed
      if (s < 30) px = *(const float4*)(xp + (s + 2) * 32);
    } else {
      asm volatile("s_waitcnt vmcnt(0)" ::: "memory");  // tail: W(31) landed
    }
    __builtin_amdgcn_sched_barrier(0);  // ds_reads must stay below the waits

    bf16x8 ah0 = *(const bf16x8*)&XhSp(p)[swzi32(rA0, g)];
    bf16x8 ah1 = *(const bf16x8*)&XhSp(p)[swzi32(rA1, g)];
    bf16x8 al0 = *(const bf16x8*)&XlSp(p)[swzi32(rA0, g)];
    bf16x8 al1 = *(const bf16x8*)&XlSp(p)[swzi32(rA1, g)];
    bf16x8 bh0 = *(const bf16x8*)&WhSp(p)[swzi32(rB0, g)];
    bf16x8 bh1 = *(const bf16x8*)&WhSp(p)[swzi32(rB1, g)];
    bf16x8 bh2 = *(const bf16x8*)&WhSp(p)[swzi32(rB2, g)];
    bf16x8 bl0 = *(const bf16x8*)&WlSp(p)[swzi32(rB0, g)];
    bf16x8 bl1 = *(const bf16x8*)&WlSp(p)[swzi32(rB1, g)];
    bf16x8 bl2 = *(const bf16x8*)&WlSp(p)[swzi32(rB2, g)];

    __builtin_amdgcn_s_setprio(1);
    acc[0][0] = __builtin_amdgcn_mfma_f32_16x16x32_bf16(ah0, bh0, acc[0][0], 0,0,0);
    acc[0][0] = __builtin_amdgcn_mfma_f32_16x16x32_bf16(ah0, bl0, acc[0][0], 0,0,0);
    acc[0][0] = __builtin_amdgcn_mfma_f32_16x16x32_bf16(al0, bh0, acc[0][0], 0,0,0);
    acc[0][1] = __builtin_amdgcn_mfma_f32_16x16x32_bf16(ah0, bh1, acc[0][1], 0,0,0);
    acc[0][1] = __builtin_amdgcn_mfma_f32_16x16x32_bf16(ah0, bl1, acc[0][1], 0,0,0);
    acc[0][1] = __builtin_amdgcn_mfma_f32_16x16x32_bf16(al0, bh1, acc[0][1], 0,0,0);
    acc[0][2] = __builtin_amdgcn_mfma_f32_16x16x32_bf16(ah0, bh2, acc[0][2], 0,0,0);
    acc[0][2] = __builtin_amdgcn_mfma_f32_16x16x32_bf16(ah0, bl2, acc[0][2], 0,0,0);
    acc[0][2] = __builtin_amdgcn_mfma_f32_16x16x32_bf16(al0, bh2, acc[0][2], 0,0,0);
    acc[1][0] = __builtin_amdgcn_mfma_f32_16x16x32_bf16(ah1, bh0, acc[1][0], 0,0,0);
    acc[1][0] = __builtin_amdgcn_mfma_f32_16x16x32_bf16(ah1, bl0, acc[1][0], 0,0,0);
    acc[1][0] = __builtin_amdgcn_mfma_f32_16x16x32_bf16(al1, bh0, acc[1][0], 0,0,0);
    acc[1][1] = __builtin_amdgcn_mfma_f32_16x16x32_bf16(ah1, bh1, acc[1][1], 0,0,0);
    acc[1][1] = __builtin_amdgcn_mfma_f32_16x16x32_bf16(ah1, bl1, acc[1][1], 0,0,0);
    acc[1][1] = __builtin_amdgcn_mfma_f32_16x16x32_bf16(al1, bh1, acc[1][1], 0,0,0);
    acc[1][2] = __builtin_amdgcn_mfma_f32_16x16x32_bf16(ah1, bh2, acc[1][2], 0,0,0);
    acc[1][2] = __builtin_amdgcn_mfma_f32_16x16x32_bf16(ah1, bl2, acc[1][2], 0,0,0);
    acc[1][2] = __builtin_amdgcn_mfma_f32_16x16x32_bf16(al1, bh2, acc[1][2], 0,0,0);
    __builtin_amdgcn_s_setprio(0);

    asm volatile("s_waitcnt lgkmcnt(0)" ::: "memory");
    __builtin_amdgcn_s_barrier();
    __builtin_amdgcn_sched_barrier(0);
  }

  // Epilogue: D[m=16i+4g+r][n=48w+16j+li]
#pragma unroll
  for (int i = 0; i < 2; ++i)
#pragma unroll
    for (int j = 0; j < 3; ++j) {
      const int H3 = 48 * w + 16 * j + li;
#pragma unroll
      for (int r = 0; r < 4; ++r) {
        const int mrow = 16 * i + 4 * g + r;
        const float vv = acc[i][j][r];
        if (H3 < 64) {
          const unsigned short hb = f2bf(vv);
          const int off = (b * SEQ + n0 + mrow) * HS + H3;
          qh[off] = hb; ql[off] = f2bf(vv - bf2f(hb));
        } else if (H3 < 128) {
          const unsigned short hb = f2bf(vv);
          const int off = (b * SEQ + n0 + mrow) * HS + (H3 - 64);
          kh[off] = hb; kl[off] = f2bf(vv - bf2f(hb));
        } else {
          vt[(b * HS + (H3 - 128)) * SEQ + n0 + mrow] = f2bf(vv);
        }
      }
    }
}

// ---------------------------------------------------------------------------
// Flash attention, round 8: r6 structure (best, 56.9us) at 16 WAVES (1024
// thr) = 4 waves/SIMD (was 2). Same tiles, same LDS layout/traffic, same
// total MFMA; finer wave decomposition to double latency-hiding TLP:
//   QK wave (qg=w&1, kf=w>>1): 32 q x 16 keys  (4 ds_read + 12 MFMA)
//   PV wave (pg=w&1, ks2=(w>>1)&3, hh=w>>3): 32q x 32keys x 32h (4 MFMA)
//   staging: 1 seg per array per wave (16 segs, same bytes via gld16)
// Deferred PV (T15), V 3-buf, Pt 2 time-parities, one barrier/iter - as r6.
// Pt slab/swizzle layout byte-identical to r6 (writer roles renamed).
// ---------------------------------------------------------------------------
__global__ __launch_bounds__(1024) void attn_mfma(
    const unsigned short* __restrict__ qh, const unsigned short* __restrict__ ql,
    const unsigned short* __restrict__ kh, const unsigned short* __restrict__ kl,
    const unsigned short* __restrict__ vt, float* __restrict__ out) {
  __shared__ __align__(16) unsigned char SM[155648];
  // layout: Kh[p] @ p*16384 (2x16KB)           [0 .. 32K)
  //         Kl[p] @ 32768 + p*16384 (2x16KB)   [32K .. 64K)
  //         Vt[v] @ 65536 + v*16384 (3x16KB)   [64K .. 112K)
  //         Pt    @ 114688, 8 slabs x 2 time-parities x 1280 ush (40KB)
  unsigned short* const PtS = (unsigned short*)(SM + 114688);

  const int t  = threadIdx.x;
  const int l  = t & 63;
  const int li = l & 15;
  const int g  = l >> 4;
  const int w  = t >> 6;        // 0..15
  const int qg = w & 1;         // QK role: q-half
  const int kf = w >> 1;        // QK role: 16-key group 0..7
  const int ks2 = (w >> 1) & 3; // PV role: 32-key slice
  const int hh  = w >> 3;       // PV role: 32-h half
  const int b  = blockIdx.y;
  const int q0 = blockIdx.x << 6;

  // Persistent Q fragments, 2 q-sets (B[k=h][n=q], n=li), rows 32qg+16qs+li.
  bf16x8 qfh[2][2], qfl[2][2];
#pragma unroll
  for (int qs = 0; qs < 2; ++qs) {
    const unsigned short* qrh = qh + (b * SEQ + q0 + 32 * qg + 16 * qs + li) * HS;
    const unsigned short* qrl = ql + (b * SEQ + q0 + 32 * qg + 16 * qs + li) * HS;
    qfh[qs][0] = *(const bf16x8*)&qrh[8 * g];
    qfh[qs][1] = *(const bf16x8*)&qrh[32 + 8 * g];
    qfl[qs][0] = *(const bf16x8*)&qrl[8 * g];
    qfl[qs][1] = *(const bf16x8*)&qrl[32 + 8 * g];
  }

  // gld16 lane constants. K segs: 8 key-rows x 64 h = 1KB; seg = w.
  const int kconst = (l >> 3) * HS + (((l & 7) ^ (l >> 3)) << 3);
  // V segs: 4 h-rows x 128 keys = 1KB; chunk perm depends on seg parity.
  const int rowl = l >> 4, slot = l & 15;
  const int vc = (w & 1) ? rowl * SEQ + ((slot ^ (4 + rowl)) << 3)
                         : rowl * SEQ + ((slot ^ rowl) << 3);
  const unsigned short* khB = kh + b * SEQ * HS;
  const unsigned short* klB = kl + b * SEQ * HS;
  const unsigned short* vtB = vt + b * HS * SEQ;

  f32x4 O[2][2];                // [ht2][qs-of-pg]
#pragma unroll
  for (int i = 0; i < 2; ++i) {
    O[i][0] = (f32x4){0.f, 0.f, 0.f, 0.f};
    O[i][1] = (f32x4){0.f, 0.f, 0.f, 0.f};
  }
  float lp0 = 0.f, lp1 = 0.f;

  // Pt write constants: slab = qg + 2*(kf>>1); chunk c = 2*(kf&1) + (g>>1).
  const int slabW = qg + 2 * (kf >> 1);
  const int cW = 2 * (kf & 1) + (g >> 1);
  const int subW = (g & 1) << 2;

  auto stage = [&](int it, int pK, int vb) {
    const int kt0 = it << 7;  // 128 keys per tile
    unsigned short* const KhP = (unsigned short*)(SM + pK * 16384);
    unsigned short* const KlP = (unsigned short*)(SM + 32768 + pK * 16384);
    unsigned short* const VtP = (unsigned short*)(SM + 65536 + vb * 16384);
    gld16(khB + (kt0 + 8 * w) * HS + kconst, KhP + w * 512);
    gld16(klB + (kt0 + 8 * w) * HS + kconst, KlP + w * 512);
    gld16(vtB + 4 * w * SEQ + kt0 + vc, VtP + w * 512);
  };

  // PV of a prior tile: Pt time-parity `par`, V buffer `vb`.
  auto PV = [&](int par, int vb) {
    unsigned short* const PtP = PtS + (qg + 2 * ks2) * 2560 + par * 1280;
    unsigned short* const VtP = (unsigned short*)(SM + 65536 + vb * 16384);
    bf16x8 pb0 = *(const bf16x8*)&PtP[li * 40 + ((g ^ (li & 3)) << 3)];
    const int r1 = 16 + li;
    bf16x8 pb1 = *(const bf16x8*)&PtP[r1 * 40 + ((g ^ (r1 & 3)) << 3)];
    __builtin_amdgcn_s_setprio(1);
#pragma unroll
    for (int ht2 = 0; ht2 < 2; ++ht2) {
      const int vrow = 32 * hh + 16 * ht2 + li;
      bf16x8 va = *(const bf16x8*)&VtP[swzi128(vrow, 4 * ks2 + g)];
      O[ht2][0] = __builtin_amdgcn_mfma_f32_16x16x32_bf16(va, pb0, O[ht2][0], 0,0,0);
      O[ht2][1] = __builtin_amdgcn_mfma_f32_16x16x32_bf16(va, pb1, O[ht2][1], 0,0,0);
    }
    __builtin_amdgcn_s_setprio(0);
  };

  stage(0, 0, 0);
  __syncthreads();            // drains tile 0 -> K[0], V[0] ready

  int vbn = 1;                // (it+1)%3
  int vbp = 2;                // (it-1)%3 (unused at it=0)
  for (int it = 0; it < 32; ++it) {
    const int p = it & 1;
    if (it < 31) stage(it + 1, p ^ 1, vbn);  // flies during compute of tile it

    unsigned short* const KhS = (unsigned short*)(SM + p * 16384);
    unsigned short* const KlS = (unsigned short*)(SM + 32768 + p * 16384);

    // QK^T(it): this wave's 16 keys (16kf + 4g + r) x its 32 q.
    f32x4 S[2];
    S[0] = (f32x4){-32.f, -32.f, -32.f, -32.f};
    S[1] = (f32x4){-32.f, -32.f, -32.f, -32.f};
    __builtin_amdgcn_s_setprio(1);
#pragma unroll
    for (int khf = 0; khf < 2; ++khf) {
      const int row = 16 * kf + li;
      bf16x8 akh = *(const bf16x8*)&KhS[swzi64(row, 4 * khf + g)];
      bf16x8 akl = *(const bf16x8*)&KlS[swzi64(row, 4 * khf + g)];
      S[0] = __builtin_amdgcn_mfma_f32_16x16x32_bf16(akh, qfh[0][khf], S[0], 0,0,0);
      S[0] = __builtin_amdgcn_mfma_f32_16x16x32_bf16(akh, qfl[0][khf], S[0], 0,0,0);
      S[0] = __builtin_amdgcn_mfma_f32_16x16x32_bf16(akl, qfh[0][khf], S[0], 0,0,0);
      S[1] = __builtin_amdgcn_mfma_f32_16x16x32_bf16(akh, qfh[1][khf], S[1], 0,0,0);
      S[1] = __builtin_amdgcn_mfma_f32_16x16x32_bf16(akh, qfl[1][khf], S[1], 0,0,0);
      S[1] = __builtin_amdgcn_mfma_f32_16x16x32_bf16(akl, qfh[1][khf], S[1], 0,0,0);
    }
    __builtin_amdgcn_s_setprio(0);

    // PV of PREVIOUS tile (other time-parity Pt + V[vbp]); independent of
    // S(it) -> overlaps the exp chain below.
    if (it > 0) PV(p ^ 1, vbp);

    // exp2, truncate to bf16, write Pt (parity p), accumulate l.
#pragma unroll
    for (int qs = 0; qs < 2; ++qs) {
      unsigned pu[4];
      float ls = 0.f;
#pragma unroll
      for (int r = 0; r < 4; ++r) {
        const float pe = exp2f(S[qs][r]);
        pu[r] = __float_as_uint(pe);
        ls += __uint_as_float(pu[r] & 0xffff0000u);
      }
      if (qs == 0) lp0 += ls; else lp1 += ls;
      const unsigned p01 = __builtin_amdgcn_perm(pu[1], pu[0], 0x07060302u);
      const unsigned p23 = __builtin_amdgcn_perm(pu[3], pu[2], 0x07060302u);
      const int qrow = 16 * qs + li;
      const int addr = qrow * 40 + (((cW ^ (qrow & 3))) << 3) + subW;
      int2 pv; pv.x = (int)p01; pv.y = (int)p23;
      *(int2*)&PtS[slabW * 2560 + p * 1280 + addr] = pv;
    }

    // ONE barrier/iter: drains tile it+1 staging + orders Pt/V/K reuse.
    __syncthreads();

    vbn = (vbn == 2) ? 0 : vbn + 1;
    vbp = (vbp == 2) ? 0 : vbp + 1;
  }

  // Drain: PV of tile 31 (Pt parity 1, V[31%3=1]).
  PV(1, 1);

  // reduce l over g (wave's 16 keys spread over g-quads)
  lp0 += __shfl_xor(lp0, 16); lp0 += __shfl_xor(lp0, 32);
  lp1 += __shfl_xor(lp1, 16); lp1 += __shfl_xor(lp1, 32);

  // Merge. OTm [0,64K) = K buffers (consumed); Lm 2KB in V[0] (not read by
  // PV(31), which reads V[1]+Pt) -- disjoint, no extra barrier needed.
  float* const OTm = (float*)SM;               // 16 x [32q][32h] f32 = 64KB
  float* const Lm  = (float*)(SM + 65536);     // [16 qk-waves][32 q]
#pragma unroll
  for (int ht2 = 0; ht2 < 2; ++ht2)
#pragma unroll
    for (int qs = 0; qs < 2; ++qs) {
      float4 o4;
      o4.x = O[ht2][qs][0]; o4.y = O[ht2][qs][1];
      o4.z = O[ht2][qs][2]; o4.w = O[ht2][qs][3];
      // sub-array id: (pg*2 + hh)*4 + ks2 ; within: [16qs+li][32h]
      *(float4*)&OTm[(((qg * 2 + hh) * 4 + ks2) << 10)
                     + (16 * qs + li) * 32 + 16 * ht2 + 4 * g] = o4;
    }
  if (g == 0) { Lm[w * 32 + li] = lp0; Lm[w * 32 + 16 + li] = lp1; }
  __syncthreads();

  // final: thread t -> q = t>>4 (64), hseg = (t&15)*4; sum 4 key-slices.
  {
    const int q = t >> 4, hseg = (t & 15) << 2;
    const int qq = q & 31, qgf = q >> 5;
    const int hhf = hseg >> 5, hsub = hseg & 31;
    float lF = 0.f;
#pragma unroll
    for (int kff = 0; kff < 8; ++kff) lF += Lm[(qgf + 2 * kff) * 32 + qq];
    float4 a = {0.f, 0.f, 0.f, 0.f};
#pragma unroll
    for (int k2 = 0; k2 < 4; ++k2) {
      const float* Ob = OTm + (((qgf * 2 + hhf) * 4 + k2) << 10) + qq * 32 + hsub;
      float4 u = *(const float4*)Ob;
      a.x += u.x; a.y += u.y; a.z += u.z; a.w += u.w;
    }
    const float inv = 1.f / lF;
    a.x *= inv; a.y *= inv; a.z *= inv; a.w *= inv;
    *(float4*)(out + (b * SEQ + q0 + q) * HS + hseg) = a;
  }
}

// ---------------------------------------------------------------------------
extern "C" void kernel_launch(void* const* d_in, const int* in_sizes, int n_in,
                              void* d_out, int out_size, void* d_ws,
                              size_t ws_size, hipStream_t stream) {
  const float* x  = (const float*)d_in[0];
  const float* Wk = (const float*)d_in[1];
  const float* Wq = (const float*)d_in[2];
  const float* Wv = (const float*)d_in[3];
  float* out = (float*)d_out;

  unsigned short* us = (unsigned short*)d_ws;
  unsigned short* qh = us + 0 * (1 << 20);   // [B][N][H] bf16 hi
  unsigned short* ql = us + 1 * (1 << 20);   // [B][N][H] bf16 lo
  unsigned short* kh = us + 2 * (1 << 20);
  unsigned short* kl = us + 3 * (1 << 20);
  unsigned short* vt = us + 4 * (1 << 20);   // [B][H][N] bf16
  unsigned short* Wh = us + 5 * (1 << 20);   // [192][1024] bf16 hi
  unsigned short* Wl = Wh + 192 * 1024;      // [192][1024] bf16 lo

  wprep<<<192, 256, 0, stream>>>(Wk, Wq, Wv, Wh, Wl);
  qkv_x1<<<512, 256, 0, stream>>>(x, Wh, Wl, qh, ql, kh, kl, vt);
  attn_mfma<<<dim3(64, NB), 1024, 0, stream>>>(qh, ql, kh, kl, vt, out);
}